// Round 6
// baseline (67.500 us; speedup 1.0000x reference)
//
#include <hip/hip_runtime.h>

// Problem constants from reference: B=16, S=4096, F=1024, units fp32, mask int32.
#define B_ 16
#define S_ 4096
#define F_ 1024
#define F4_ (F_ / 4)    // float4 per output row = 256
#define NT_ 256         // threads per block
#define EPT_ (S_ / NT_) // mask elements per thread = 16

// Fused, 1 output token row per block: grid (T, B). Each block:
//  1) scans the whole mask row (redundant across blocks, but L2-resident:
//     total mask = 256 KB) -> row length + the source index of rank t0,
//  2) gathers that one unit row (4 KB) and stores it (or zeros) to out.
// Scatter memory structure identical to the best-measured R1 kernel:
// one float4 load + one float4 store per thread, 33K independent blocks.
__global__ __launch_bounds__(NT_) void fused_kernel(const float4* __restrict__ units,
                                                    const int* __restrict__ mask,
                                                    float4* __restrict__ out, int T) {
    const int b   = blockIdx.y;
    const int t0  = blockIdx.x;          // this block's output token slot
    const int tid = threadIdx.x;
    const int lane = tid & 63;
    const int wid  = tid >> 6;           // 4 waves

    // ---- 1) block scan of mask row (each thread owns 16 consecutive elems) ----
    const int4* mrow = (const int4*)(mask + b * S_);
    int4 m[EPT_ / 4];
#pragma unroll
    for (int k = 0; k < EPT_ / 4; ++k) m[k] = mrow[tid * (EPT_ / 4) + k];

    int local = 0;
#pragma unroll
    for (int k = 0; k < EPT_ / 4; ++k) local += m[k].x + m[k].y + m[k].z + m[k].w;

    // wave-inclusive scan of per-thread sums
    int incl = local;
#pragma unroll
    for (int d = 1; d < 64; d <<= 1) {
        int n = __shfl_up(incl, d, 64);
        if (lane >= d) incl += n;
    }

    __shared__ int wsum[4];
    __shared__ int woff[4];
    __shared__ int slen;
    __shared__ int ssrc;
    if (lane == 63) wsum[wid] = incl;
    __syncthreads();
    if (tid == 0) {
        int acc = 0;
#pragma unroll
        for (int w = 0; w < 4; ++w) { woff[w] = acc; acc += wsum[w]; }
        slen = acc;
    }
    __syncthreads();

    // thread-exclusive rank of this thread's first set bit; deposit the
    // source index whose rank == t0 (at most one thread hits it).
    int r = woff[wid] + (incl - local);
    if (t0 >= r && t0 < r + local) {     // only the owning thread walks its bits
        const int s0 = tid * EPT_;
#pragma unroll
        for (int k = 0; k < EPT_ / 4; ++k) {
            const int mv[4] = {m[k].x, m[k].y, m[k].z, m[k].w};
#pragma unroll
            for (int j = 0; j < 4; ++j) {
                if (mv[j]) {
                    if (r == t0) ssrc = s0 + k * 4 + j;
                    ++r;
                }
            }
        }
    }
    __syncthreads();

    // ---- 2) gather + store one output row ----
    float4 v = make_float4(0.f, 0.f, 0.f, 0.f);
    if (t0 < slen) {
        v = units[((size_t)(b * S_ + ssrc)) * F4_ + tid];
    }
    out[((size_t)b * (size_t)T + t0) * F4_ + tid] = v;
}

extern "C" void kernel_launch(void* const* d_in, const int* in_sizes, int n_in,
                              void* d_out, int out_size, void* d_ws, size_t ws_size,
                              hipStream_t stream) {
    const float* units = (const float*)d_in[0];
    const int*   mask  = (const int*)d_in[1];
    float*       out   = (float*)d_out;

    const int T = out_size / (B_ * F_);   // harness sized d_out as B*T*F

    dim3 grid((unsigned)T, B_);
    fused_kernel<<<grid, NT_, 0, stream>>>((const float4*)units, mask,
                                           (float4*)out, T);
}

// Round 7
// 51.038 us; speedup vs baseline: 1.3225x; 1.3225x over previous
//
#include <hip/hip_runtime.h>

// Problem constants from reference: B=16, S=4096, F=1024, units fp32, mask int32.
#define B_ 16
#define S_ 4096
#define F_ 1024
#define F4_ (F_ / 4)   // float4 per output row = 256

// Best-measured structure (R1, 50.7 us). Experiments that regressed:
//   nontemporal hints (53.0), 8-rows-per-block batching (55.7),
//   fused scan ROWS_8 (53.7), fused scan ROWS_1 (67.5).
// Scatter = ~265 MB at ~6.0 TB/s ~= 95% of the m13 copy ceiling.

// One block per batch row. 1024 threads; each thread scans 4 mask elems (int4).
// Produces src[b*S_ + p] = s for the p-th masked subtoken of row b, and lens[b].
__global__ __launch_bounds__(1024) void pos_kernel(const int* __restrict__ mask,
                                                   int* __restrict__ src,
                                                   int* __restrict__ lens) {
    const int b   = blockIdx.x;
    const int tid = threadIdx.x;

    const int4 m = ((const int4*)(mask + b * S_))[tid];
    const int local = m.x + m.y + m.z + m.w;

    const int lane = tid & 63;
    const int wid  = tid >> 6;

    // wave-inclusive scan of per-thread sums
    int incl = local;
#pragma unroll
    for (int d = 1; d < 64; d <<= 1) {
        int n = __shfl_up(incl, d, 64);
        if (lane >= d) incl += n;
    }

    __shared__ int wsum[16];
    __shared__ int woff[17];
    if (lane == 63) wsum[wid] = incl;
    __syncthreads();
    if (tid == 0) {
        int acc = 0;
#pragma unroll
        for (int w = 0; w < 16; ++w) { woff[w] = acc; acc += wsum[w]; }
        woff[16] = acc;
        lens[b] = acc;
    }
    __syncthreads();

    int p = woff[wid] + (incl - local);   // exclusive prefix for this thread
    const int s0 = tid * 4;
    int* srow = src + b * S_;
    if (m.x) srow[p++] = s0;
    if (m.y) srow[p++] = s0 + 1;
    if (m.z) srow[p++] = s0 + 2;
    if (m.w) srow[p]   = s0 + 3;
}

// One block per output token row (grid: T x B). 256 threads, one float4 each.
__global__ __launch_bounds__(F4_) void scatter_kernel(const float4* __restrict__ units,
                                                      const int* __restrict__ src,
                                                      const int* __restrict__ lens,
                                                      float4* __restrict__ out, int T) {
    const int t = blockIdx.x;
    const int b = blockIdx.y;

    float4 v = make_float4(0.f, 0.f, 0.f, 0.f);
    const int len = lens[b];   // block-uniform load, broadcast
    if (t < len) {
        const int s = src[b * S_ + t];
        v = units[((size_t)(b * S_ + s)) * F4_ + threadIdx.x];
    }
    out[((size_t)b * (size_t)T + t) * F4_ + threadIdx.x] = v;
}

extern "C" void kernel_launch(void* const* d_in, const int* in_sizes, int n_in,
                              void* d_out, int out_size, void* d_ws, size_t ws_size,
                              hipStream_t stream) {
    const float* units = (const float*)d_in[0];
    const int*   mask  = (const int*)d_in[1];
    float*       out   = (float*)d_out;

    const int T = out_size / (B_ * F_);   // harness sized d_out as B*T*F

    int* src  = (int*)d_ws;               // B_*S_ ints
    int* lens = src + B_ * S_;            // B_ ints

    pos_kernel<<<B_, 1024, 0, stream>>>(mask, src, lens);

    dim3 grid((unsigned)T, B_);
    scatter_kernel<<<grid, F4_, 0, stream>>>((const float4*)units, src, lens,
                                             (float4*)out, T);
}